// Round 9
// baseline (16.090 us; speedup 1.0000x reference)
//
#include <hip/hip_runtime.h>

// EdgeNetwork: messages[e,i] = sum_j relu(edges[e,:] @ W[:, i*32+j] + b[i*32+j]) * states[e,j]
// M = 65536 rows, F=16, D=32.
//
// Round-9 (micro-pass on the 16.0us R8 skeleton; probe T1 serial-residual vs
// T2 fixed-overhead):
//  1. W gather issued FIRST (feeds the barrier-critical ds_writes); edges/
//     states loads issue after and their latency hides under the bf16 pack.
//  2. Staging loads: 16x dwordx2 (uint2) instead of 32x dword -- half the
//     VMEM issue slots, same bytes, same coalescing.
//  3. Cross-half combine: 8x v_permlane32_swap_b32 + 8 adds (VALU pipe)
//     replace 16 __shfl_xor bpermutes (ds pipe). Pairing pn[i]<->pn[i+8]
//     puts combined pn[i] in lanes<32 and pn[i+8] in lanes>=32 == exactly
//     the store layout -> branchless float4 stores (h-branch gone too).
// Mapping (proven R7/R8): per n (16 per wave), one bf16 MFMA 32x32x16:
// D_n[j][e] = sum_f W[f][n*32+j] * edges[e][f]; lane owns edge e = lane&31,
// acc reg r owns j = (r&3)+8*(r>>2)+4*(lane>>5); states lane-local in regs;
// loop LDS = 1 ds_read_b128/iter; zero-bias fast path via ballot+LDS OR.

typedef __attribute__((ext_vector_type(8))) short short8;
typedef __attribute__((ext_vector_type(16))) float f32x16;

__device__ __forceinline__ unsigned short f2bf(float x) {
    union { float f; unsigned u; } v; v.f = x;
    return (unsigned short)((v.u + 0x7FFFu + ((v.u >> 16) & 1u)) >> 16);  // RNE
}

#define PACK2(lo, hi) ((int)(((hi) & 0xFFFF0000u) | ((lo) >> 16)))

__global__ __launch_bounds__(512, 2)
void edgenet_kernel(const float* __restrict__ states,
                    const float* __restrict__ edges,
                    const float* __restrict__ W,
                    const float* __restrict__ bias,
                    float* __restrict__ out)
{
    // Wlds chunk (n*64 + l) [16B each]: A[row=l&31][k=(l>>5)*8+t] = W[f=(l>>5)*8+t][n*32+(l&31)]
    __shared__ unsigned short Wlds[16384];   // 32 KB, A-frag order bf16
    __shared__ float Blds[1024];             // C-frag order bias
    __shared__ unsigned long long nzv[8];

    const int tid  = threadIdx.x;
    const int wave = tid >> 6;
    const int lane = tid & 63;
    const int ecol = lane & 31;              // edge within tile (MFMA D column)
    const int h    = lane >> 5;
    const int tile  = blockIdx.x * 4 + (wave >> 1);   // 512 blocks * 4 = 2048 tiles
    const int nbase = (wave & 1) << 4;                // 0 or 16
    const long long row = (long long)tile * 32 + ecol;

    // ---- 1) W gather FIRST: thread owns columns c0=2*tid, c0+1; 16 dwordx2,
    //         coalesced (512B/wave-instr), round-half-up to bf16 bits ----
    unsigned av[16], bv[16];
    {
        const uint2* w2 = reinterpret_cast<const uint2*>(W);
        #pragma unroll
        for (int f = 0; f < 16; ++f) {
            const uint2 v = w2[(f << 9) + tid];       // dwords f*1024 + 2*tid (+1)
            av[f] = v.x + 0x8000u;
            bv[f] = v.y + 0x8000u;
        }
    }

    // ---- 2) edges + states prefetch (issue after W; drains under pack) ----
    const float* ep = edges + row * 16 + h * 8;
    const float4 ev0 = *reinterpret_cast<const float4*>(ep);
    const float4 ev1 = *reinterpret_cast<const float4*>(ep + 4);
    const float* sp = states + row * 32 + h * 4;      // j_r = (r&3) + 8*(r>>2) + 4h
    const float4 sv0 = *reinterpret_cast<const float4*>(sp);
    const float4 sv1 = *reinterpret_cast<const float4*>(sp + 8);
    const float4 sv2 = *reinterpret_cast<const float4*>(sp + 16);
    const float4 sv3 = *reinterpret_cast<const float4*>(sp + 24);

    // ---- 3) pack + 4x ds_write_b128 in A-frag order ----
    {
        int4* w4 = reinterpret_cast<int4*>(Wlds);
        const int c0 = tid << 1;
        const int n = c0 >> 5, j = c0 & 31;           // j even
        int4 alo, ahi, blo, bhi;
        alo.x = PACK2(av[0], av[1]);  alo.y = PACK2(av[2],  av[3]);
        alo.z = PACK2(av[4], av[5]);  alo.w = PACK2(av[6],  av[7]);
        ahi.x = PACK2(av[8], av[9]);  ahi.y = PACK2(av[10], av[11]);
        ahi.z = PACK2(av[12],av[13]); ahi.w = PACK2(av[14], av[15]);
        blo.x = PACK2(bv[0], bv[1]);  blo.y = PACK2(bv[2],  bv[3]);
        blo.z = PACK2(bv[4], bv[5]);  blo.w = PACK2(bv[6],  bv[7]);
        bhi.x = PACK2(bv[8], bv[9]);  bhi.y = PACK2(bv[10], bv[11]);
        bhi.z = PACK2(bv[12],bv[13]); bhi.w = PACK2(bv[14], bv[15]);
        w4[(n << 6) + j]      = alo;   // l = j        (f 0..7)
        w4[(n << 6) + j + 32] = ahi;   // l = j  + 32  (f 8..15)
        w4[(n << 6) + j + 1]  = blo;   // l = j+1      (f 0..7)
        w4[(n << 6) + j + 33] = bhi;   // l = j+1 + 32 (f 8..15)
    }

    // ---- stage bias (C-frag order) + zero-detect ----
    {
        const int i0 = tid;
        int r = i0 & 15, hh = (i0 >> 4) & 1, nn = i0 >> 5;
        const float b0 = bias[(nn << 5) + (r & 3) + ((r >> 2) << 3) + (hh << 2)];
        const int i1 = tid + 512;
        r = i1 & 15; hh = (i1 >> 4) & 1; nn = i1 >> 5;
        const float b1 = bias[(nn << 5) + (r & 3) + ((r >> 2) << 3) + (hh << 2)];
        Blds[i0] = b0;
        Blds[i1] = b1;
        const unsigned nz = __float_as_uint(b0) | __float_as_uint(b1);
        const unsigned long long bal = __ballot(nz != 0u);
        if (lane == 0) nzv[wave] = bal;
    }
    __syncthreads();
    const bool bias_zero =
        ((nzv[0] | nzv[1] | nzv[2] | nzv[3] | nzv[4] | nzv[5] | nzv[6] | nzv[7]) == 0ULL);

    // ---- B fragment: B[k=h*8+t][col=ecol] = edges[row][h*8+t] ----
    short8 bfrag;
    bfrag[0] = (short)f2bf(ev0.x); bfrag[1] = (short)f2bf(ev0.y);
    bfrag[2] = (short)f2bf(ev0.z); bfrag[3] = (short)f2bf(ev0.w);
    bfrag[4] = (short)f2bf(ev1.x); bfrag[5] = (short)f2bf(ev1.y);
    bfrag[6] = (short)f2bf(ev1.z); bfrag[7] = (short)f2bf(ev1.w);

    // s[r] = states[row][(r&3) + 8*(r>>2) + 4h]  (aligned with acc reg r)
    const float s[16] = {sv0.x, sv0.y, sv0.z, sv0.w,
                         sv1.x, sv1.y, sv1.z, sv1.w,
                         sv2.x, sv2.y, sv2.z, sv2.w,
                         sv3.x, sv3.y, sv3.z, sv3.w};

    const unsigned short* wl = &Wlds[(((unsigned)nbase << 6) + (unsigned)lane) << 3];
    const float* bb = &Blds[(nbase << 5) + (h << 4)];

    float pn[16];

    if (bias_zero) {
        // ---- fast path: C = 0, loop LDS = 1 ds_read_b128 per iter ----
        f32x16 z;
        #pragma unroll
        for (int r = 0; r < 16; ++r) z[r] = 0.f;
        #pragma unroll
        for (int i = 0; i < 16; ++i) {
            const short8 afrag = *reinterpret_cast<const short8*>(wl + i * 512);
            const f32x16 acc = __builtin_amdgcn_mfma_f32_32x32x16_bf16(afrag, bfrag, z, 0, 0, 0);
            float p0 = 0.f, p1 = 0.f, p2 = 0.f, p3 = 0.f;
            #pragma unroll
            for (int r = 0; r < 16; r += 4) {
                p0 = fmaf(fmaxf(acc[r+0], 0.f), s[r+0], p0);
                p1 = fmaf(fmaxf(acc[r+1], 0.f), s[r+1], p1);
                p2 = fmaf(fmaxf(acc[r+2], 0.f), s[r+2], p2);
                p3 = fmaf(fmaxf(acc[r+3], 0.f), s[r+3], p3);
            }
            pn[i] = (p0 + p1) + (p2 + p3);
        }
    } else {
        // ---- general path: bias via MFMA C-operand (broadcast ds_reads) ----
        #pragma unroll
        for (int i = 0; i < 16; ++i) {
            f32x16 acc;
            #pragma unroll
            for (int r = 0; r < 16; ++r) acc[r] = bb[i * 32 + r];
            const short8 afrag = *reinterpret_cast<const short8*>(wl + i * 512);
            acc = __builtin_amdgcn_mfma_f32_32x32x16_bf16(afrag, bfrag, acc, 0, 0, 0);
            float p0 = 0.f, p1 = 0.f, p2 = 0.f, p3 = 0.f;
            #pragma unroll
            for (int r = 0; r < 16; r += 4) {
                p0 = fmaf(fmaxf(acc[r+0], 0.f), s[r+0], p0);
                p1 = fmaf(fmaxf(acc[r+1], 0.f), s[r+1], p1);
                p2 = fmaf(fmaxf(acc[r+2], 0.f), s[r+2], p2);
                p3 = fmaf(fmaxf(acc[r+3], 0.f), s[r+3], p3);
            }
            pn[i] = (p0 + p1) + (p2 + p3);
        }
    }

    // ---- combine halves: v_permlane32_swap pairs (i, i+8). After swap:
    //      a' = {a.lo, b.lo}, b' = {a.hi, b.hi}  ->  q = a' + b' holds
    //      combined pn[i] in lanes<32 and combined pn[i+8] in lanes>=32,
    //      which is exactly the branchless store layout. ----
    float q[8];
    #pragma unroll
    for (int i = 0; i < 8; ++i) {
        float a = pn[i], b = pn[i + 8];
        asm volatile("v_permlane32_swap_b32 %0, %1" : "+v"(a), "+v"(b));
        q[i] = a + b;
    }

    // ---- store: lane (e=lane&31, h) writes out[row][nbase + h*8 .. +8) ----
    float* op = out + row * 32 + nbase + h * 8;
    *reinterpret_cast<float4*>(op)     = make_float4(q[0], q[1], q[2], q[3]);
    *reinterpret_cast<float4*>(op + 4) = make_float4(q[4], q[5], q[6], q[7]);
}

extern "C" void kernel_launch(void* const* d_in, const int* in_sizes, int n_in,
                              void* d_out, int out_size, void* d_ws, size_t ws_size,
                              hipStream_t stream) {
    (void)in_sizes; (void)n_in; (void)d_ws; (void)ws_size; (void)out_size;
    const float* states = (const float*)d_in[0];
    const float* edges  = (const float*)d_in[1];
    const float* W      = (const float*)d_in[2];
    const float* bias   = (const float*)d_in[3];
    float* out          = (float*)d_out;

    hipLaunchKernelGGL(edgenet_kernel, dim3(512), dim3(512), 0, stream,
                       states, edges, W, bias, out);
}